// Round 1
// 228.893 us; speedup vs baseline: 1.0304x; 1.0304x over previous
//
#include <hip/hip_runtime.h>
#include <cstdint>

// B=16384, D=512, U=512, K=D+U=1024, N=4U=2048
#define HU 8388608  // 16384*512, offset of c-part in out

typedef __attribute__((ext_vector_type(8))) short short8_t;
typedef __attribute__((ext_vector_type(4))) float float4_t;
typedef __attribute__((ext_vector_type(16))) float float16_t;
typedef __attribute__((ext_vector_type(4))) unsigned int uint4_t;
typedef __attribute__((ext_vector_type(2))) unsigned int uint2_t;

__device__ __forceinline__ unsigned short f2bf(float x) {
    unsigned u = __builtin_bit_cast(unsigned, x);
    u += 0x7fffu + ((u >> 16) & 1u);  // RNE
    return (unsigned short)(u >> 16);
}

__device__ __forceinline__ void gll16(const void* g, const void* lds) {
    __builtin_amdgcn_global_load_lds(
        (const __attribute__((address_space(1))) unsigned int*)(uintptr_t)g,
        (__attribute__((address_space(3))) unsigned int*)(unsigned int)(uintptr_t)lds,
        16, 0, 0);
}

__device__ __forceinline__ float sigm(float x) {
    return __builtin_amdgcn_rcpf(1.f + __expf(-x));
}
__device__ __forceinline__ float tanhfast(float x) {
    float ax = fabsf(x);
    float e = __expf(-2.f * ax);
    float r = (1.f - e) * __builtin_amdgcn_rcpf(1.f + e);
    return copysignf(r, x);
}

// ---------- merged pre-pass: blocks [0,8192) concat+cvt, [8192,10240) transpose ----------
__global__ __launch_bounds__(256) void prep(const float* __restrict__ x,
                                            const float* __restrict__ h,
                                            const float* __restrict__ W,
                                            const float* __restrict__ R,
                                            unsigned short* __restrict__ xh,
                                            unsigned short* __restrict__ btw) {
    __shared__ float t[32 * 33];
    int bid = blockIdx.x;
    int tid = threadIdx.x;
    if (bid < 8192) {
        int n = bid * 256 + tid;
        int e8 = n * 8;
        int row = e8 >> 10, col = e8 & 1023;
        const float* src = (col < 512) ? (x + row * 512 + col) : (h + row * 512 + (col - 512));
        float4_t lo = *(const float4_t*)src;
        float4_t hi = *(const float4_t*)(src + 4);
        uint4_t o;
        o.x = (unsigned)f2bf(lo.x) | ((unsigned)f2bf(lo.y) << 16);
        o.y = (unsigned)f2bf(lo.z) | ((unsigned)f2bf(lo.w) << 16);
        o.z = (unsigned)f2bf(hi.x) | ((unsigned)f2bf(hi.y) << 16);
        o.w = (unsigned)f2bf(hi.z) | ((unsigned)f2bf(hi.w) << 16);
        *(uint4_t*)(xh + e8) = o;
    } else {
        // Gate-major layout for 256x256-tile main kernel:
        // Btw[n''][k] = bf16(Wall[k][g*512 + u]) with n'' = ub*128 + g*32 + uo, u = ub*32+uo
        int gid = bid - 8192;
        int kt = gid & 31, ub = (gid >> 5) & 15, g = gid >> 9;
        int ky = tid >> 3, ux4 = (tid & 7) * 4;
        int kg = kt * 32 + ky;
        int col = g * 512 + ub * 32 + ux4;
        const float* src = (kg < 512) ? (W + (size_t)kg * 2048 + col)
                                      : (R + (size_t)(kg - 512) * 2048 + col);
        float4_t v = *(const float4_t*)src;
        t[ky * 33 + ux4 + 0] = v.x;
        t[ky * 33 + ux4 + 1] = v.y;
        t[ky * 33 + ux4 + 2] = v.z;
        t[ky * 33 + ux4 + 3] = v.w;
        __syncthreads();
        int uo = tid >> 3, kx4 = (tid & 7) * 4;
        unsigned short o0 = f2bf(t[(kx4 + 0) * 33 + uo]);
        unsigned short o1 = f2bf(t[(kx4 + 1) * 33 + uo]);
        unsigned short o2 = f2bf(t[(kx4 + 2) * 33 + uo]);
        unsigned short o3 = f2bf(t[(kx4 + 3) * 33 + uo]);
        uint2_t p;
        p.x = (unsigned)o0 | ((unsigned)o1 << 16);
        p.y = (unsigned)o2 | ((unsigned)o3 << 16);
        *(uint2_t*)(btw + (size_t)(ub * 128 + g * 32 + uo) * 1024 + kt * 32 + kx4) = p;
    }
}

// ---------- main: 256x256 tile, BK=32, 8 waves, 4-deep LDS ring, counted vmcnt ----------
// Pipeline: stage tile t+3 while computing tile t; vmcnt(8) per tile (never 0 in main loop).
// Slot reuse safe: slot (t+3)&3 last read at tile t-1, barrier-separated.
// Gates live in the 4 B-fragments per wave -> LSTM epilogue entirely in registers.

#define BAR()                                    \
    do {                                         \
        asm volatile("" ::: "memory");           \
        __builtin_amdgcn_s_barrier();            \
        asm volatile("" ::: "memory");           \
    } while (0)

// One phase: 6 ds_read_b128 + (optional) 2 global_load_lds + barrier + 8 MFMA
#define PHASE(BO, SO, KK, DOSTAGE, TS)                                                       \
    do {                                                                                     \
        short8_t a0 = *(const short8_t*)&lds[(BO) + aro[0][KK]];                             \
        short8_t a1 = *(const short8_t*)&lds[(BO) + aro[1][KK]];                             \
        short8_t b0 = *(const short8_t*)&lds[(BO) + bro[0][KK]];                             \
        short8_t b1 = *(const short8_t*)&lds[(BO) + bro[1][KK]];                             \
        short8_t b2 = *(const short8_t*)&lds[(BO) + bro[2][KK]];                             \
        short8_t b3 = *(const short8_t*)&lds[(BO) + bro[3][KK]];                             \
        if (DOSTAGE) {                                                                       \
            if ((KK) == 0) {                                                                 \
                gll16(aS0 + (TS) * 32, &lds[(SO) + dA0]);                                    \
                gll16(bS0 + (TS) * 32, &lds[(SO) + dB0]);                                    \
            } else {                                                                         \
                gll16(aS1 + (TS) * 32, &lds[(SO) + dA1]);                                    \
                gll16(bS1 + (TS) * 32, &lds[(SO) + dB1]);                                    \
            }                                                                                \
        }                                                                                    \
        BAR();                                                                               \
        __builtin_amdgcn_s_setprio(1);                                                       \
        acc[0][0] = __builtin_amdgcn_mfma_f32_32x32x16_bf16(a0, b0, acc[0][0], 0, 0, 0);     \
        acc[0][1] = __builtin_amdgcn_mfma_f32_32x32x16_bf16(a0, b1, acc[0][1], 0, 0, 0);     \
        acc[0][2] = __builtin_amdgcn_mfma_f32_32x32x16_bf16(a0, b2, acc[0][2], 0, 0, 0);     \
        acc[0][3] = __builtin_amdgcn_mfma_f32_32x32x16_bf16(a0, b3, acc[0][3], 0, 0, 0);     \
        acc[1][0] = __builtin_amdgcn_mfma_f32_32x32x16_bf16(a1, b0, acc[1][0], 0, 0, 0);     \
        acc[1][1] = __builtin_amdgcn_mfma_f32_32x32x16_bf16(a1, b1, acc[1][1], 0, 0, 0);     \
        acc[1][2] = __builtin_amdgcn_mfma_f32_32x32x16_bf16(a1, b2, acc[1][2], 0, 0, 0);     \
        acc[1][3] = __builtin_amdgcn_mfma_f32_32x32x16_bf16(a1, b3, acc[1][3], 0, 0, 0);     \
        __builtin_amdgcn_s_setprio(0);                                                       \
    } while (0)

__global__ __launch_bounds__(512, 2) void lstm_main(
    const unsigned short* __restrict__ xh,   // [16384][1024] bf16
    const unsigned short* __restrict__ btw,  // [2048][1024] bf16, gate-major rows
    const float* __restrict__ c_tm1,         // [16384][512]
    const float* __restrict__ pw,            // [512][3]
    const float* __restrict__ bias,          // [2048]
    float* __restrict__ out)                 // [2][16384][512]
{
    // 4 ring slots x (A: 256rows x 32k + B: 256rows x 32k) bf16 = 4 x 32 KB = 128 KB
    __shared__ __align__(16) short lds[65536];

    int tid = threadIdx.x;
    int lane = tid & 63, wid = tid >> 6;
    int wrow = wid & 3, wcol = wid >> 2;     // 4 M-waves x 2 N-waves
    int l31 = lane & 31, hfl = lane >> 5;

    // XCD-aware swizzle: each XCD (bid&7) gets a contiguous 8-mb x 8-nb chunk
    int bid = blockIdx.x;
    int xcd = bid & 7, local = bid >> 3;
    int mb = xcd * 8 + (local & 7);          // [0,64)
    int nb = local >> 3;                     // [0,8)

    // ---- staging setup: gll16 writes (uniform base + lane*16B); pre-swizzled global src ----
    // LDS(row, slot) holds global chunk slot ^ ((row>>1)&3); row = 64B = 4 chunks of 16B
    int r0 = wid * 16 + (lane >> 2);         // rows 0..127 (half 0)
    int r1 = 128 + r0;                       // rows 128..255 (half 1)
    int sl = lane & 3;
    int g0 = sl ^ ((r0 >> 1) & 3);
    int g1 = sl ^ ((r1 >> 1) & 3);
    const unsigned short* aS0 = xh + (size_t)(mb * 256 + r0) * 1024 + g0 * 8;
    const unsigned short* aS1 = xh + (size_t)(mb * 256 + r1) * 1024 + g1 * 8;
    const unsigned short* bS0 = btw + (size_t)(nb * 256 + r0) * 1024 + g0 * 8;
    const unsigned short* bS1 = btw + (size_t)(nb * 256 + r1) * 1024 + g1 * 8;
    int dA0 = wid * 512;                     // wave-uniform LDS dest (shorts), half 0
    int dA1 = (8 + wid) * 512;               // half 1
    int dB0 = 8192 + dA0, dB1 = 8192 + dA1;

    // ---- LDS read offsets (shorts within slot), swizzle folded in ----
    int aro[2][2], bro[4][2];
#pragma unroll
    for (int m = 0; m < 2; ++m) {
        int r = wrow * 64 + m * 32 + l31;
        int sw = (r >> 1) & 3;
#pragma unroll
        for (int kk = 0; kk < 2; ++kk)
            aro[m][kk] = r * 32 + (((kk * 2 + hfl) ^ sw) * 8);
    }
#pragma unroll
    for (int g = 0; g < 4; ++g) {
        int r = wcol * 128 + g * 32 + l31;   // B row = block col; g = gate
        int sw = (r >> 1) & 3;
#pragma unroll
        for (int kk = 0; kk < 2; ++kk)
            bro[g][kk] = 8192 + r * 32 + (((kk * 2 + hfl) ^ sw) * 8);
    }

    float16_t acc[2][4];
#pragma unroll
    for (int m = 0; m < 2; ++m)
#pragma unroll
        for (int g = 0; g < 4; ++g)
#pragma unroll
            for (int r = 0; r < 16; ++r) acc[m][g][r] = 0.f;

    // ---- prologue: stage tiles 0,1,2 (12 loads/thread); wait so tile 0 resident ----
#pragma unroll
    for (int t = 0; t < 3; ++t) {
        int bo = t * 16384;
        gll16(aS0 + t * 32, &lds[bo + dA0]);
        gll16(bS0 + t * 32, &lds[bo + dB0]);
        gll16(aS1 + t * 32, &lds[bo + dA1]);
        gll16(bS1 + t * 32, &lds[bo + dB1]);
    }
    asm volatile("s_waitcnt vmcnt(8)" ::: "memory");  // tiles 1,2 still in flight
    BAR();

    // ---- main loop: 32 K-tiles of 32; stage t+3; vmcnt(8) per tile ----
#pragma unroll 4
    for (int t = 0; t < 28; ++t) {
        int bo = (t & 3) * 16384;
        int so = ((t + 3) & 3) * 16384;
        PHASE(bo, so, 0, 1, t + 3);
        BAR();
        PHASE(bo, so, 1, 1, t + 3);
        asm volatile("s_waitcnt vmcnt(8)" ::: "memory");  // tile t+1 resident, t+2/t+3 in flight
        BAR();
    }
    // t=28: stage tile 31
    PHASE(0, 49152, 0, 1, 31);
    BAR();
    PHASE(0, 49152, 1, 1, 31);
    asm volatile("s_waitcnt vmcnt(8)" ::: "memory");
    BAR();
    // t=29
    PHASE(16384, 0, 0, 0, 0);
    BAR();
    PHASE(16384, 0, 1, 0, 0);
    asm volatile("s_waitcnt vmcnt(4)" ::: "memory");
    BAR();
    // t=30
    PHASE(32768, 0, 0, 0, 0);
    BAR();
    PHASE(32768, 0, 1, 0, 0);
    asm volatile("s_waitcnt vmcnt(0)" ::: "memory");
    BAR();
    // t=31
    PHASE(49152, 0, 0, 0, 0);
    BAR();
    PHASE(49152, 0, 1, 0, 0);

    // ---- register epilogue: lane holds all 4 gates of (row, unit) in acc[m][0..3] ----
    // 32x32 C/D: col=lane&31 (unit), row=(reg&3)+8*(reg>>2)+4*(lane>>5)
    int u = nb * 64 + wcol * 32 + l31;
    float bi = bias[u], bf = bias[512 + u], bg2 = bias[1024 + u], bo2 = bias[1536 + u];
    float pwi = pw[u * 3 + 0], pwf = pw[u * 3 + 1], pwo = pw[u * 3 + 2];
    int rbase = mb * 256 + wrow * 64 + 4 * hfl;
#pragma unroll
    for (int m = 0; m < 2; ++m) {
#pragma unroll
        for (int reg = 0; reg < 16; ++reg) {
            int grow = rbase + m * 32 + (reg & 3) + 8 * (reg >> 2);
            size_t off = (size_t)grow * 512 + u;
            float c1 = c_tm1[off];
            float iv = sigm(acc[m][0][reg] + bi + c1 * pwi);
            float fv = sigm(acc[m][1][reg] + bf + c1 * pwf);
            float gv = tanhfast(acc[m][2][reg] + bg2);
            float cc = fv * c1 + iv * gv;
            float ov = sigm(acc[m][3][reg] + bo2 + cc * pwo);
            out[off] = ov * tanhfast(cc);
            out[HU + off] = cc;
        }
    }
}

extern "C" void kernel_launch(void* const* d_in, const int* in_sizes, int n_in,
                              void* d_out, int out_size, void* d_ws, size_t ws_size,
                              hipStream_t stream) {
    const float* x    = (const float*)d_in[0];
    const float* h    = (const float*)d_in[1];
    const float* c    = (const float*)d_in[2];
    const float* W    = (const float*)d_in[3];
    const float* R    = (const float*)d_in[4];
    const float* pw   = (const float*)d_in[5];
    const float* bias = (const float*)d_in[6];
    float* out = (float*)d_out;

    unsigned short* xh  = (unsigned short*)d_ws;                        // 33,554,432 B
    unsigned short* btw = (unsigned short*)((char*)d_ws + 33554432u);   // + 4,194,304 B

    prep<<<10240, 256, 0, stream>>>(x, h, W, R, xh, btw);
    lstm_main<<<512, 512, 0, stream>>>(xh, btw, c, pw, bias, out);
}